// Round 13
// baseline (103.852 us; speedup 1.0000x reference)
//
#include <hip/hip_runtime.h>

#define BB 32
#define SS 22
#define NN 2048
#define HH 8
#define DKK 8
#define PP 6

__device__ __forceinline__ float rfl(float x) {
    return __uint_as_float((unsigned)__builtin_amdgcn_readfirstlane((int)__float_as_uint(x)));
}

__global__ __attribute__((amdgpu_flat_work_group_size(512, 512),
                          amdgpu_waves_per_eu(8, 8)))
// wave = head (h wave-uniform -> M/U in SGPRs); lane = pair. Per-lane VGPR state
// ~28-30 -> fits the 32-reg allocation the compiler emits at the 8-wave target
// (R10/R12) with ZERO spill. Occupancy follows the attribute (R10/R11/R12).
void mha_kernel(
    const float* __restrict__ q, const float* __restrict__ k, const float* __restrict__ v,
    const int* __restrict__ mask,
    const float* __restrict__ Wq, const float* __restrict__ bq,
    const float* __restrict__ Wk, const float* __restrict__ bk,
    const float* __restrict__ Wv, const float* __restrict__ bv,
    const float* __restrict__ Wc, const float* __restrict__ bc,
    const float* __restrict__ Wf, const float* __restrict__ bf,
    float* __restrict__ out)
{
    __shared__ float Ms[HH][9];
    __shared__ float Us[HH][3];
    __shared__ unsigned mb[SS];
    __shared__ __align__(16) float wflS[SS][8];    // [s][p], p<6 = Wf[p][s], else 0
    __shared__ float offL[HH];                     // bf[p] + bc0*sum_s Wf[p,s]; p>=6: 0
    __shared__ __align__(16) float4 kvL[SS][64];   // {kx,ky,vx,vy} per (t, pair-in-block)
    __shared__ float mergeL[HH][PP][64];           // per-head partial outputs

    const int tid = threadIdx.x;
    const float2* qp = (const float2*)q;
    const float2* kp = (const float2*)k;
    const float2* vp = (const float2*)v;

    // --- per-block precompute of the collapsed weight forms (512 threads) ---
    if (tid < 72) {
        int hh = tid / 9, ij = tid - hh * 9, i = ij / 3, j = ij - i * 3;
        float acc = 0.f;
        for (int d = 0; d < DKK; ++d) {
            int c = hh * DKK + d;
            float a  = (i == 0) ? Wq[2 * c] : (i == 1) ? Wq[2 * c + 1] : bq[c];
            float bb = (j == 0) ? Wk[2 * c] : (j == 1) ? Wk[2 * c + 1] : bk[c];
            acc = fmaf(a, bb, acc);
        }
        Ms[hh][ij] = acc * (1.4426950408889634f / 64.f);  // fold 1/DK^2 and log2(e)
    } else if (tid < 96) {
        int r = tid - 72, hh = r / 3, j = r - hh * 3;
        float acc = 0.f;
        for (int d = 0; d < DKK; ++d) {
            int c = hh * DKK + d;
            float a = (j == 0) ? Wv[2 * c] : (j == 1) ? Wv[2 * c + 1] : bv[c];
            acc = fmaf(a, Wc[c], acc);
        }
        Us[hh][j] = acc;
    } else if (tid < 96 + SS) {
        int s = tid - 96;
        unsigned bitsv = 0;
        for (int t = 0; t < SS; ++t)
            if (mask[s * SS + t] != 0) bitsv |= (1u << t);
        mb[s] = bitsv;
    } else if (tid < 120 + HH) {
        int p = tid - 120;
        float acc = 0.f;
        if (p < PP) {
            float ssum = 0.f;
            for (int t = 0; t < SS; ++t) ssum += Wf[p * SS + t];
            acc = fmaf(bc[0], ssum, bf[p]);
        }
        offL[p] = acc;
    } else if (tid >= 128 && tid < 128 + SS * 8) {
        int idx = tid - 128, s = idx >> 3, j = idx & 7;
        wflS[s][j] = (j < PP) ? Wf[j * SS + s] : 0.f;
    }
    // stage K/V for this block's 64 pairs into LDS (coalesced 8B/lane loads)
    for (int idx = tid; idx < SS * 64; idx += 512) {
        int t = idx >> 6, p2 = idx & 63;
        int pairL = blockIdx.x * 64 + p2;
        int bb_ = pairL >> 11, nn_ = pairL & (NN - 1);
        int gix = (bb_ * SS + t) * NN + nn_;
        float2 kk = kp[gix], vv = vp[gix];
        kvL[t][p2] = make_float4(kk.x, kk.y, vv.x, vv.y);
    }
    __syncthreads();

    const int h    = tid >> 6;                 // wave-uniform head
    const int pr   = tid & 63;                 // pair-in-block (lane)
    const int pair = blockIdx.x * 64 + pr;
    const int b    = pair >> 11;               // NN = 2048
    const int n    = pair & (NN - 1);
    const int baseIdx = b * SS * NN + n;       // float2 index; + s*NN per q row

    // M/U wave-uniform -> force to SGPRs (zero VGPR cost)
    const float m00 = rfl(Ms[h][0]), m01 = rfl(Ms[h][1]), m02 = rfl(Ms[h][2]);
    const float m10 = rfl(Ms[h][3]), m11 = rfl(Ms[h][4]), m12 = rfl(Ms[h][5]);
    const float m20 = rfl(Ms[h][6]), m21 = rfl(Ms[h][7]), m22 = rfl(Ms[h][8]);
    const float u0  = rfl(Us[h][0]), u1  = rfl(Us[h][1]), u2  = rfl(Us[h][2]);

    // fully-masked-row value: only computed if some row is all-masked (block-uniform,
    // probability ~1e-5; keeps 22 ds_reads out of the common path)
    bool allNZ = true;
#pragma unroll
    for (int s2 = 0; s2 < SS; ++s2) allNZ = allNZ && (mb[s2] != 0);
    float csU = 0.f;
    if (!allNZ) {
        float SVx = 0.f, SVy = 0.f;
#pragma unroll
        for (int t = 0; t < SS; ++t) { float4 kv = kvL[t][pr]; SVx += kv.z; SVy += kv.w; }
        csU = fmaf(u0, SVx, fmaf(u1, SVy, (float)SS * u2)) * (1.f / (float)SS);
    }

    float o0 = 0.f, o1 = 0.f, o2 = 0.f, o3 = 0.f, o4 = 0.f, o5 = 0.f;
#pragma unroll
    for (int s = 0; s < SS; ++s) {
        const unsigned bits = (unsigned)__builtin_amdgcn_readfirstlane((int)mb[s]);
        const float2 qq = qp[baseIdx + s * NN];   // 64 consecutive n -> fully coalesced
        float cs;
        if (bits == 0) {
            cs = csU;   // reference softmax degenerates to uniform 1/S
        } else {
            const float g0 = fmaf(qq.x, m00, fmaf(qq.y, m10, m20));
            const float g1 = fmaf(qq.x, m01, fmaf(qq.y, m11, m21));
            const float g2 = fmaf(qq.x, m02, fmaf(qq.y, m12, m22));
            float S = 0.f, Dx = 0.f, Dy = 0.f;
#pragma unroll
            for (int t = 0; t < SS; ++t) {
                if (bits & (1u << t)) {           // wave-uniform skip (~half the exps)
                    float4 kv = kvL[t][pr];       // 64 distinct lanes -> full-width b128
                    float e = __builtin_amdgcn_exp2f(fmaf(g0, kv.x, fmaf(g1, kv.y, g2)));
                    S += e;
                    Dx = fmaf(e, kv.z, Dx);
                    Dy = fmaf(e, kv.w, Dy);
                }
                // masked entries: exp(-2^15 - m) == 0.0f exactly in the reference
            }
            // dot = u0*Dx + u1*Dy + u2*S
            cs = fmaf(u0, Dx, fmaf(u1, Dy, u2 * S)) * __builtin_amdgcn_rcpf(S);
        }
        // per-head partial epilogue: o[p] += cs * Wf[p][s]  (broadcast LDS reads)
        const float4 wa = *(const float4*)&wflS[s][0];
        const float2 wb = *(const float2*)&wflS[s][4];
        o0 = fmaf(cs, wa.x, o0); o1 = fmaf(cs, wa.y, o1); o2 = fmaf(cs, wa.z, o2);
        o3 = fmaf(cs, wa.w, o3); o4 = fmaf(cs, wb.x, o4); o5 = fmaf(cs, wb.y, o5);
    }

    // head merge: each wave deposits its 6 partials, then 384 threads reduce over h
    mergeL[h][0][pr] = o0; mergeL[h][1][pr] = o1; mergeL[h][2][pr] = o2;
    mergeL[h][3][pr] = o3; mergeL[h][4][pr] = o4; mergeL[h][5][pr] = o5;
    __syncthreads();

    if (tid < PP * 64) {
        const int p   = tid >> 6;
        const int pr2 = tid & 63;
        float val = offL[p];
#pragma unroll
        for (int w = 0; w < HH; ++w) val += mergeL[w][p][pr2];
        const int pair2 = blockIdx.x * 64 + pr2;
        const int b2 = pair2 >> 11, n2 = pair2 & (NN - 1);
        out[(b2 * PP + p) * NN + n2] = val;   // consecutive n2 -> coalesced
    }
}

extern "C" void kernel_launch(void* const* d_in, const int* in_sizes, int n_in,
                              void* d_out, int out_size, void* d_ws, size_t ws_size,
                              hipStream_t stream) {
    const float* q  = (const float*)d_in[0];
    const float* k  = (const float*)d_in[1];
    const float* v  = (const float*)d_in[2];
    const int* mask = (const int*)d_in[3];
    const float* Wq = (const float*)d_in[4];
    const float* bq = (const float*)d_in[5];
    const float* Wk = (const float*)d_in[6];
    const float* bk = (const float*)d_in[7];
    const float* Wv = (const float*)d_in[8];
    const float* bv = (const float*)d_in[9];
    const float* Wc = (const float*)d_in[10];
    const float* bc = (const float*)d_in[11];
    const float* Wf = (const float*)d_in[12];
    const float* bf = (const float*)d_in[13];
    float* out = (float*)d_out;

    dim3 grid(BB * NN / 64), block(512);
    hipLaunchKernelGGL(mha_kernel, grid, block, 0, stream,
                       q, k, v, mask, Wq, bq, Wk, bk, Wv, bv, Wc, bc, Wf, bf, out);
}

// Round 14
// 47.918 us; speedup vs baseline: 2.1673x; 2.1673x over previous
//
#include <hip/hip_runtime.h>

#define BB 32
#define SS 22
#define NN 2048
#define HH 8
#define DKK 8
#define PP 6

__global__ __launch_bounds__(256, 4) void mha_kernel(
    const float* __restrict__ q, const float* __restrict__ k, const float* __restrict__ v,
    const int* __restrict__ mask,
    const float* __restrict__ Wq, const float* __restrict__ bq,
    const float* __restrict__ Wk, const float* __restrict__ bk,
    const float* __restrict__ Wv, const float* __restrict__ bv,
    const float* __restrict__ Wc, const float* __restrict__ bc,
    const float* __restrict__ Wf, const float* __restrict__ bf,
    float* __restrict__ out)
{
    __shared__ float Ms[HH][9];
    __shared__ float Us[HH][3];
    __shared__ unsigned mb[SS];
    __shared__ __align__(16) float wflS[SS][8];    // [s][p], p<6 = Wf[p][s], else 0
    __shared__ float offL[HH];                     // bf[p] + bc0*sum_s Wf[p,s]; p>=6: 0
    __shared__ __align__(16) float4 kvL[SS][64];   // {kx,ky,vx,vy} per (t, pair-in-block)

    const int tid = threadIdx.x;
    const float2* qp = (const float2*)q;
    const float2* kp = (const float2*)k;
    const float2* vp = (const float2*)v;

    // --- per-block precompute of the collapsed weight forms ---
    if (tid < 72) {
        int hh = tid / 9, ij = tid - hh * 9, i = ij / 3, j = ij - i * 3;
        float acc = 0.f;
        for (int d = 0; d < DKK; ++d) {
            int c = hh * DKK + d;
            float a  = (i == 0) ? Wq[2 * c] : (i == 1) ? Wq[2 * c + 1] : bq[c];
            float bb = (j == 0) ? Wk[2 * c] : (j == 1) ? Wk[2 * c + 1] : bk[c];
            acc = fmaf(a, bb, acc);
        }
        Ms[hh][ij] = acc * (1.4426950408889634f / 64.f);  // fold 1/DK^2 and log2(e)
    } else if (tid < 96) {
        int r = tid - 72, hh = r / 3, j = r - hh * 3;
        float acc = 0.f;
        for (int d = 0; d < DKK; ++d) {
            int c = hh * DKK + d;
            float a = (j == 0) ? Wv[2 * c] : (j == 1) ? Wv[2 * c + 1] : bv[c];
            acc = fmaf(a, Wc[c], acc);
        }
        Us[hh][j] = acc;
    } else if (tid < 96 + SS) {
        int s = tid - 96;
        unsigned bitsv = 0;
        for (int t = 0; t < SS; ++t)
            if (mask[s * SS + t] != 0) bitsv |= (1u << t);
        mb[s] = bitsv;
    } else if (tid >= 120 && tid < 120 + HH) {
        int p = tid - 120;
        float acc = 0.f;
        if (p < PP) {
            float ssum = 0.f;
            for (int t = 0; t < SS; ++t) ssum += Wf[p * SS + t];
            acc = fmaf(bc[0], ssum, bf[p]);
        }
        offL[p] = acc;
    }
    for (int idx = tid; idx < SS * 8; idx += 256) {
        int s = idx >> 3, j = idx & 7;
        wflS[s][j] = (j < PP) ? Wf[j * SS + s] : 0.f;
    }
    // stage K/V for this block's 64 pairs into LDS (coalesced 8B/lane loads)
    for (int idx = tid; idx < SS * 64; idx += 256) {
        int t = idx >> 6, p2 = idx & 63;
        int pairL = blockIdx.x * 64 + p2;
        int bb_ = pairL >> 11, nn_ = pairL & (NN - 1);
        int gix = (bb_ * SS + t) * NN + nn_;
        float2 kk = kp[gix], vv = vp[gix];
        kvL[t][p2] = make_float4(kk.x, kk.y, vv.x, vv.y);
    }
    __syncthreads();

    // Lane layout: pg = lane&15 -> 16 pairs per wave; hg = lane>>4 -> head-group.
    // Thread computes heads {2hg, 2hg+1}: each kvL read feeds 2 heads in-thread
    // and is 4-way broadcast across hg -> 8x less LDS traffic than wave-per-head.
    const int lane = tid & 63;
    const int wid  = tid >> 6;
    const int pg   = lane & 15;
    const int hg   = lane >> 4;
    const int h0   = hg * 2, h1 = hg * 2 + 1;
    const int pin  = wid * 16 + pg;               // pair-in-block (0..63)
    const int pair = blockIdx.x * 64 + pin;
    const int b    = pair >> 11;                  // NN = 2048
    const int n    = pair & (NN - 1);
    const int baseIdx = b * SS * NN + n;          // float2 index; + s*NN per q row

    // M/U for this thread's two heads (per-lane -> VGPRs, static-indexed scalars)
    const float mA0 = Ms[h0][0], mA1 = Ms[h0][1], mA2 = Ms[h0][2];
    const float mA3 = Ms[h0][3], mA4 = Ms[h0][4], mA5 = Ms[h0][5];
    const float mA6 = Ms[h0][6], mA7 = Ms[h0][7], mA8 = Ms[h0][8];
    const float uA0 = Us[h0][0], uA1 = Us[h0][1], uA2 = Us[h0][2];
    const float mB0 = Ms[h1][0], mB1 = Ms[h1][1], mB2 = Ms[h1][2];
    const float mB3 = Ms[h1][3], mB4 = Ms[h1][4], mB5 = Ms[h1][5];
    const float mB6 = Ms[h1][6], mB7 = Ms[h1][7], mB8 = Ms[h1][8];
    const float uB0 = Us[h1][0], uB1 = Us[h1][1], uB2 = Us[h1][2];

    // fully-masked-row value (block-uniform rare path), hoisted
    float csUsum = 0.f;
    {
        bool anyZ = false;
        for (int s2 = 0; s2 < SS; ++s2) anyZ = anyZ || (mb[s2] == 0);
        if (anyZ) {
            float SVx = 0.f, SVy = 0.f;
#pragma unroll
            for (int t = 0; t < SS; ++t) { float4 kv = kvL[t][pin]; SVx += kv.z; SVy += kv.w; }
            float cA = fmaf(uA0, SVx, fmaf(uA1, SVy, (float)SS * uA2)) * (1.f / (float)SS);
            float cB = fmaf(uB0, SVx, fmaf(uB1, SVy, (float)SS * uB2)) * (1.f / (float)SS);
            csUsum = cA + cB;
        }
    }

    float o0 = 0.f, o1 = 0.f, o2 = 0.f, o3 = 0.f, o4 = 0.f, o5 = 0.f;
#pragma unroll 2
    for (int s = 0; s < SS; ++s) {
        const unsigned bits = (unsigned)__builtin_amdgcn_readfirstlane((int)mb[s]);
        const float2 qq = qp[baseIdx + s * NN];   // 16 consecutive n x4 broadcast
        float cs;
        if (bits == 0) {
            cs = csUsum;  // reference softmax degenerates to uniform 1/S
        } else {
            const float gA0 = fmaf(qq.x, mA0, fmaf(qq.y, mA3, mA6));
            const float gA1 = fmaf(qq.x, mA1, fmaf(qq.y, mA4, mA7));
            const float gA2 = fmaf(qq.x, mA2, fmaf(qq.y, mA5, mA8));
            const float gB0 = fmaf(qq.x, mB0, fmaf(qq.y, mB3, mB6));
            const float gB1 = fmaf(qq.x, mB1, fmaf(qq.y, mB4, mB7));
            const float gB2 = fmaf(qq.x, mB2, fmaf(qq.y, mB5, mB8));
            float S0 = 0.f, Dx0 = 0.f, Dy0 = 0.f;
            float S1 = 0.f, Dx1 = 0.f, Dy1 = 0.f;
            // wave-uniform skip (~half the exps); compile-time t; one 16B read
            // feeds 2 heads (10 VALU + 2 exp per read -> ds latency hidden by ILP)
#pragma unroll
            for (int t = 0; t < SS; ++t) {
                if (bits & (1u << t)) {
                    float4 kv = kvL[t][pin];
                    float e0 = __builtin_amdgcn_exp2f(fmaf(gA0, kv.x, fmaf(gA1, kv.y, gA2)));
                    float e1 = __builtin_amdgcn_exp2f(fmaf(gB0, kv.x, fmaf(gB1, kv.y, gB2)));
                    S0 += e0; Dx0 = fmaf(e0, kv.z, Dx0); Dy0 = fmaf(e0, kv.w, Dy0);
                    S1 += e1; Dx1 = fmaf(e1, kv.z, Dx1); Dy1 = fmaf(e1, kv.w, Dy1);
                }
                // masked entries: exp(-2^15 - m) == 0.0f exactly in the reference
            }
            float cA = fmaf(uA0, Dx0, fmaf(uA1, Dy0, uA2 * S0)) * __builtin_amdgcn_rcpf(S0);
            float cB = fmaf(uB0, Dx1, fmaf(uB1, Dy1, uB2 * S1)) * __builtin_amdgcn_rcpf(S1);
            cs = cA + cB;
        }
        // merge the 4 head-groups: butterfly over hg bits (lane bits 4,5)
        cs += __shfl_xor(cs, 16);
        cs += __shfl_xor(cs, 32);
        // per-p epilogue accumulation (wflS[s] broadcast reads)
        const float4 wa = *(const float4*)&wflS[s][0];
        const float2 wb = *(const float2*)&wflS[s][4];
        o0 = fmaf(cs, wa.x, o0); o1 = fmaf(cs, wa.y, o1); o2 = fmaf(cs, wa.z, o2);
        o3 = fmaf(cs, wa.w, o3); o4 = fmaf(cs, wb.x, o4); o5 = fmaf(cs, wb.y, o5);
    }

    if (hg == 0) {   // 16 lanes, consecutive n -> coalesced 64B segments per p
        out[(b * PP + 0) * NN + n] = o0 + offL[0];
        out[(b * PP + 1) * NN + n] = o1 + offL[1];
        out[(b * PP + 2) * NN + n] = o2 + offL[2];
        out[(b * PP + 3) * NN + n] = o3 + offL[3];
        out[(b * PP + 4) * NN + n] = o4 + offL[4];
        out[(b * PP + 5) * NN + n] = o5 + offL[5];
    }
}

extern "C" void kernel_launch(void* const* d_in, const int* in_sizes, int n_in,
                              void* d_out, int out_size, void* d_ws, size_t ws_size,
                              hipStream_t stream) {
    const float* q  = (const float*)d_in[0];
    const float* k  = (const float*)d_in[1];
    const float* v  = (const float*)d_in[2];
    const int* mask = (const int*)d_in[3];
    const float* Wq = (const float*)d_in[4];
    const float* bq = (const float*)d_in[5];
    const float* Wk = (const float*)d_in[6];
    const float* bk = (const float*)d_in[7];
    const float* Wv = (const float*)d_in[8];
    const float* bv = (const float*)d_in[9];
    const float* Wc = (const float*)d_in[10];
    const float* bc = (const float*)d_in[11];
    const float* Wf = (const float*)d_in[12];
    const float* bf = (const float*)d_in[13];
    float* out = (float*)d_out;

    dim3 grid(BB * NN / 64), block(256);
    hipLaunchKernelGGL(mha_kernel, grid, block, 0, stream,
                       q, k, v, mask, Wq, bq, Wk, bk, Wv, bv, Wc, bc, Wf, bf, out);
}

// Round 15
// 44.826 us; speedup vs baseline: 2.3168x; 1.0690x over previous
//
#include <hip/hip_runtime.h>

#define BB 32
#define SS 22
#define NN 2048
#define HH 8
#define DKK 8
#define PP 6

__global__ __attribute__((amdgpu_flat_work_group_size(256, 256),
                          amdgpu_waves_per_eu(8, 8)))
// attr(8,8): occupancy follows this attribute (R10/R12: 75% vs R2/R11/R14: ~40%),
// and the allocator emits exactly 32 VGPRs at the 8-wave target. This kernel is
// RESTRUCTURED to fit 32 regs (1 head/thread, single accumulator) -> no spill.
void mha_kernel(
    const float* __restrict__ q, const float* __restrict__ k, const float* __restrict__ v,
    const int* __restrict__ mask,
    const float* __restrict__ Wq, const float* __restrict__ bq,
    const float* __restrict__ Wk, const float* __restrict__ bk,
    const float* __restrict__ Wv, const float* __restrict__ bv,
    const float* __restrict__ Wc, const float* __restrict__ bc,
    const float* __restrict__ Wf, const float* __restrict__ bf,
    float* __restrict__ out)
{
    __shared__ float Ms[HH][9];
    __shared__ float Us[HH][3];
    __shared__ unsigned mb[SS];
    __shared__ float wflL[HH][SS];                 // Wf rows; rows 6,7 zero
    __shared__ float offL[HH];                     // bf[p] + bc0*sum_s Wf[p,s]; p>=6: 0
    __shared__ __align__(16) float4 kvL[SS][32];   // {kx,ky,vx,vy} per (t, pair-in-block)

    const int tid = threadIdx.x;
    const float2* qp = (const float2*)q;
    const float2* kp = (const float2*)k;
    const float2* vp = (const float2*)v;

    // --- per-block precompute of the collapsed weight forms ---
    if (tid < 72) {
        int hh = tid / 9, ij = tid - hh * 9, i = ij / 3, j = ij - i * 3;
        float acc = 0.f;
        for (int d = 0; d < DKK; ++d) {
            int c = hh * DKK + d;
            float a  = (i == 0) ? Wq[2 * c] : (i == 1) ? Wq[2 * c + 1] : bq[c];
            float bb = (j == 0) ? Wk[2 * c] : (j == 1) ? Wk[2 * c + 1] : bk[c];
            acc = fmaf(a, bb, acc);
        }
        Ms[hh][ij] = acc * (1.4426950408889634f / 64.f);  // fold 1/DK^2 and log2(e)
    } else if (tid < 96) {
        int r = tid - 72, hh = r / 3, j = r - hh * 3;
        float acc = 0.f;
        for (int d = 0; d < DKK; ++d) {
            int c = hh * DKK + d;
            float a = (j == 0) ? Wv[2 * c] : (j == 1) ? Wv[2 * c + 1] : bv[c];
            acc = fmaf(a, Wc[c], acc);
        }
        Us[hh][j] = acc;
    } else if (tid < 96 + SS) {
        int s = tid - 96;
        unsigned bitsv = 0;
        for (int t = 0; t < SS; ++t)
            if (mask[s * SS + t] != 0) bitsv |= (1u << t);
        mb[s] = bitsv;
    } else if (tid >= 120 && tid < 120 + HH) {
        int p = tid - 120;
        float acc = 0.f;
        if (p < PP) {
            float ssum = 0.f;
            for (int t = 0; t < SS; ++t) ssum += Wf[p * SS + t];
            acc = fmaf(bc[0], ssum, bf[p]);
        }
        offL[p] = acc;
    }
    for (int idx = tid; idx < HH * SS; idx += 256) {
        int hh = idx / SS, t = idx - hh * SS;
        wflL[hh][t] = (hh < PP) ? Wf[hh * SS + t] : 0.f;
    }
    // stage K/V for this block's 32 pairs into LDS (coalesced 8B/lane loads)
    for (int idx = tid; idx < SS * 32; idx += 256) {
        int t = idx >> 5, p2 = idx & 31;
        int pairL = blockIdx.x * 32 + p2;
        int bb_ = pairL >> 11, nn_ = pairL & (NN - 1);
        int gix = (bb_ * SS + t) * NN + nn_;
        float2 kk = kp[gix], vv = vp[gix];
        kvL[t][p2] = make_float4(kk.x, kk.y, vv.x, vv.y);
    }
    __syncthreads();

    // Lane layout: pg = lane&7 -> 8 consecutive pairs; h = lane>>3 -> head.
    // kvL[t][pin] per wave: 8 distinct float4, 8-way broadcast -> conflict-free.
    const int lane = tid & 63;
    const int wid  = tid >> 6;
    const int pg   = lane & 7;
    const int h    = lane >> 3;
    const int pin  = wid * 8 + pg;                // pair-in-block (0..31)
    const int pair = blockIdx.x * 32 + pin;
    const int b    = pair >> 11;                  // NN = 2048
    const int n    = pair & (NN - 1);
    const int baseIdx = b * SS * NN + n;          // float2 index; + s*NN per q row

    // M/U for this thread's head (12 VGPRs)
    const float m0 = Ms[h][0], m1 = Ms[h][1], m2 = Ms[h][2];
    const float m3 = Ms[h][3], m4 = Ms[h][4], m5 = Ms[h][5];
    const float m6 = Ms[h][6], m7 = Ms[h][7], m8 = Ms[h][8];
    const float u0 = Us[h][0], u1 = Us[h][1], u2 = Us[h][2];

    float o = 0.f;
#pragma unroll 2
    for (int s = 0; s < SS; ++s) {
        const unsigned bits = (unsigned)__builtin_amdgcn_readfirstlane((int)mb[s]);
        const float2 qq = qp[baseIdx + s * NN];   // 8 consecutive n, 8-way broadcast
        float cs;
        if (bits == 0) {
            // fully-masked row (block-uniform, prob ~1e-5): uniform softmax, lazy
            float SVx = 0.f, SVy = 0.f;
            for (int t = 0; t < SS; ++t) { float4 kv = kvL[t][pin]; SVx += kv.z; SVy += kv.w; }
            cs = fmaf(u0, SVx, fmaf(u1, SVy, (float)SS * u2)) * (1.f / (float)SS);
        } else {
            const float g0 = fmaf(qq.x, m0, fmaf(qq.y, m3, m6));
            const float g1 = fmaf(qq.x, m1, fmaf(qq.y, m4, m7));
            const float g2 = fmaf(qq.x, m2, fmaf(qq.y, m5, m8));
            float S = 0.f, Dx = 0.f, Dy = 0.f;
            // static unrolled walk, wave-uniform skip (~half the exps); one
            // broadcast ds_read_b128 per active t; LDS is K/V's home -> no remat
#pragma unroll
            for (int t = 0; t < SS; ++t) {
                if (bits & (1u << t)) {
                    float4 kv = kvL[t][pin];
                    float e = __builtin_amdgcn_exp2f(fmaf(g0, kv.x, fmaf(g1, kv.y, g2)));
                    S += e;
                    Dx = fmaf(e, kv.z, Dx);
                    Dy = fmaf(e, kv.w, Dy);
                }
                // masked entries: exp(-2^15 - m) == 0.0f exactly in the reference
            }
            // dot = u0*Dx + u1*Dy + u2*S
            cs = fmaf(u0, Dx, fmaf(u1, Dy, u2 * S)) * __builtin_amdgcn_rcpf(S);
        }
        // merge heads: butterfly over the h bits (lane bits 3,4,5)
        cs += __shfl_xor(cs, 8);
        cs += __shfl_xor(cs, 16);
        cs += __shfl_xor(cs, 32);
        o = fmaf(cs, wflL[h][s], o);   // epilogue folded in (rows 6,7 zero)
    }

    if (h < PP)
        out[(b * PP + h) * NN + n] = o + offL[h];
}

extern "C" void kernel_launch(void* const* d_in, const int* in_sizes, int n_in,
                              void* d_out, int out_size, void* d_ws, size_t ws_size,
                              hipStream_t stream) {
    const float* q  = (const float*)d_in[0];
    const float* k  = (const float*)d_in[1];
    const float* v  = (const float*)d_in[2];
    const int* mask = (const int*)d_in[3];
    const float* Wq = (const float*)d_in[4];
    const float* bq = (const float*)d_in[5];
    const float* Wk = (const float*)d_in[6];
    const float* bk = (const float*)d_in[7];
    const float* Wv = (const float*)d_in[8];
    const float* bv = (const float*)d_in[9];
    const float* Wc = (const float*)d_in[10];
    const float* bc = (const float*)d_in[11];
    const float* Wf = (const float*)d_in[12];
    const float* bf = (const float*)d_in[13];
    float* out = (float*)d_out;

    dim3 grid(BB * NN / 32), block(256);
    hipLaunchKernelGGL(mha_kernel, grid, block, 0, stream,
                       q, k, v, mask, Wq, bq, Wk, bk, Wv, bv, Wc, bc, Wf, bf, out);
}

// Round 16
// 43.297 us; speedup vs baseline: 2.3986x; 1.0353x over previous
//
#include <hip/hip_runtime.h>

#define BB 32
#define SS 22
#define NN 2048
#define HH 8
#define DKK 8
#define PP 6

__global__ __attribute__((amdgpu_flat_work_group_size(256, 256),
                          amdgpu_waves_per_eu(8, 8)))
// attr(8,8): occupancy follows this attribute (R10/R12/R15); allocator emits
// 32 VGPRs at the 8-wave target -> kernel is structured to FIT 32 regs.
// This revision: head-merge moved out of the s-loop (kills the per-s serial
// rcp->3xshfl chain), g2 dropped (cancels in softmax), u2 hoisted into offL.
void mha_kernel(
    const float* __restrict__ q, const float* __restrict__ k, const float* __restrict__ v,
    const int* __restrict__ mask,
    const float* __restrict__ Wq, const float* __restrict__ bq,
    const float* __restrict__ Wk, const float* __restrict__ bk,
    const float* __restrict__ Wv, const float* __restrict__ bv,
    const float* __restrict__ Wc, const float* __restrict__ bc,
    const float* __restrict__ Wf, const float* __restrict__ bf,
    float* __restrict__ out)
{
    __shared__ float Ms[HH][6];                    // columns j<2 only (g2 dropped)
    __shared__ float Us[HH][2];                    // u0,u1 only (u2 hoisted)
    __shared__ unsigned mb[SS];
    __shared__ __align__(16) float wflS[SS][8];    // [s][p], p<6 = Wf[p][s], else 0
    __shared__ float offL[PP];                     // bf + (bc0 + sum_h u2_h)*sum_s Wf
    __shared__ __align__(16) float4 kvL[SS][32];   // {kx,ky,vx,vy} per (t, pair-in-block)

    const int tid = threadIdx.x;
    const float2* qp = (const float2*)q;
    const float2* kp = (const float2*)k;
    const float2* vp = (const float2*)v;

    // --- per-block precompute of the collapsed weight forms ---
    if (tid < 48) {
        // M[h][i][j], i in {qx,qy,1}, j in {kx,ky} (j=2/bk column cancels in softmax)
        int hh = tid / 6, ij = tid - hh * 6, i = ij >> 1, j = ij & 1;
        float acc = 0.f;
        for (int d = 0; d < DKK; ++d) {
            int c = hh * DKK + d;
            float a = (i == 0) ? Wq[2 * c] : (i == 1) ? Wq[2 * c + 1] : bq[c];
            acc = fmaf(a, Wk[2 * c + j], acc);
        }
        Ms[hh][ij] = acc * (1.4426950408889634f / 64.f);  // fold 1/DK^2 and log2(e)
    } else if (tid < 64) {
        int r = tid - 48, hh = r >> 1, j = r & 1;
        float acc = 0.f;
        for (int d = 0; d < DKK; ++d) {
            int c = hh * DKK + d;
            acc = fmaf(Wv[2 * c + j], Wc[c], acc);
        }
        Us[hh][j] = acc;
    } else if (tid < 64 + SS) {
        int s = tid - 64;
        unsigned bitsv = 0;
        for (int t = 0; t < SS; ++t)
            if (mask[s * SS + t] != 0) bitsv |= (1u << t);
        mb[s] = bitsv;
    } else if (tid >= 96 && tid < 96 + PP) {
        int p = tid - 96;
        // u2sum = sum_h u2_h = sum_c bv[c]*Wc[c]  (recomputed here: no barrier needed)
        float u2sum = 0.f;
        for (int c = 0; c < HH * DKK; ++c) u2sum = fmaf(bv[c], Wc[c], u2sum);
        float ssum = 0.f;
        for (int t = 0; t < SS; ++t) ssum += Wf[p * SS + t];
        offL[p] = fmaf(bc[0] + u2sum, ssum, bf[p]);
    }
    for (int idx = tid; idx < SS * 8; idx += 256) {
        int s = idx >> 3, j = idx & 7;
        wflS[s][j] = (j < PP) ? Wf[j * SS + s] : 0.f;
    }
    // stage K/V for this block's 32 pairs into LDS (coalesced 8B/lane loads)
    for (int idx = tid; idx < SS * 32; idx += 256) {
        int t = idx >> 5, p2 = idx & 31;
        int pairL = blockIdx.x * 32 + p2;
        int bb_ = pairL >> 11, nn_ = pairL & (NN - 1);
        int gix = (bb_ * SS + t) * NN + nn_;
        float2 kk = kp[gix], vv = vp[gix];
        kvL[t][p2] = make_float4(kk.x, kk.y, vv.x, vv.y);
    }
    __syncthreads();

    // Lane layout: pg = lane&7 -> 8 consecutive pairs; h = lane>>3 -> head.
    // kvL[t][pin] per wave: 8 distinct float4, 8-way broadcast -> conflict-free.
    const int lane = tid & 63;
    const int wid  = tid >> 6;
    const int pg   = lane & 7;
    const int h    = lane >> 3;
    const int pin  = wid * 8 + pg;                // pair-in-block (0..31)
    const int pair = blockIdx.x * 32 + pin;
    const int b    = pair >> 11;                  // NN = 2048
    const int n    = pair & (NN - 1);
    const int baseIdx = b * SS * NN + n;          // float2 index; + s*NN per q row

    // M/U for this thread's head (8 VGPRs)
    const float m00 = Ms[h][0], m01 = Ms[h][1];
    const float m10 = Ms[h][2], m11 = Ms[h][3];
    const float m20 = Ms[h][4], m21 = Ms[h][5];
    const float u0  = Us[h][0], u1  = Us[h][1];

    float o0 = 0.f, o1 = 0.f, o2 = 0.f, o3 = 0.f, o4 = 0.f, o5 = 0.f;
#pragma unroll 2
    for (int s = 0; s < SS; ++s) {
        const unsigned bits = (unsigned)__builtin_amdgcn_readfirstlane((int)mb[s]);
        const float2 qq = qp[baseIdx + s * NN];   // 8 consecutive n, 8-way broadcast
        float cs;
        if (bits == 0) {
            // fully-masked row (block-uniform, prob ~1e-5): uniform softmax, lazy
            float SVx = 0.f, SVy = 0.f;
            for (int t = 0; t < SS; ++t) { float4 kv = kvL[t][pin]; SVx += kv.z; SVy += kv.w; }
            cs = fmaf(u0, SVx, u1 * SVy) * (1.f / (float)SS);
        } else {
            const float g0 = fmaf(qq.x, m00, fmaf(qq.y, m10, m20));
            const float g1 = fmaf(qq.x, m01, fmaf(qq.y, m11, m21));
            float S = 0.f, Dx = 0.f, Dy = 0.f;
            // static unrolled walk, wave-uniform skip (~half the exps); one
            // broadcast ds_read_b128 per active t; no cross-lane ops in-loop
#pragma unroll
            for (int t = 0; t < SS; ++t) {
                if (bits & (1u << t)) {
                    float4 kv = kvL[t][pin];
                    float e = __builtin_amdgcn_exp2f(fmaf(g0, kv.x, g1 * kv.y));
                    S += e;
                    Dx = fmaf(e, kv.z, Dx);
                    Dy = fmaf(e, kv.w, Dy);
                }
                // masked entries: exp(-2^15 - m) == 0.0f exactly in the reference
            }
            cs = fmaf(u0, Dx, u1 * Dy) * __builtin_amdgcn_rcpf(S);
        }
        // per-head partial epilogue: o[p] += cs * Wf[p][s]  (broadcast LDS reads,
        // independent across s -> no serial cross-lane chain in the loop)
        const float4 wa = *(const float4*)&wflS[s][0];
        const float2 wb = *(const float2*)&wflS[s][4];
        o0 = fmaf(cs, wa.x, o0); o1 = fmaf(cs, wa.y, o1); o2 = fmaf(cs, wa.z, o2);
        o3 = fmaf(cs, wa.w, o3); o4 = fmaf(cs, wb.x, o4); o5 = fmaf(cs, wb.y, o5);
    }

    // head merge ONCE: butterfly over the h bits (lane bits 3,4,5) for each p
    o0 += __shfl_xor(o0, 8);  o0 += __shfl_xor(o0, 16); o0 += __shfl_xor(o0, 32);
    o1 += __shfl_xor(o1, 8);  o1 += __shfl_xor(o1, 16); o1 += __shfl_xor(o1, 32);
    o2 += __shfl_xor(o2, 8);  o2 += __shfl_xor(o2, 16); o2 += __shfl_xor(o2, 32);
    o3 += __shfl_xor(o3, 8);  o3 += __shfl_xor(o3, 16); o3 += __shfl_xor(o3, 32);
    o4 += __shfl_xor(o4, 8);  o4 += __shfl_xor(o4, 16); o4 += __shfl_xor(o4, 32);
    o5 += __shfl_xor(o5, 8);  o5 += __shfl_xor(o5, 16); o5 += __shfl_xor(o5, 32);

    if (h < PP) {
        float val = (h == 0) ? o0 : (h == 1) ? o1 : (h == 2) ? o2
                  : (h == 3) ? o3 : (h == 4) ? o4 : o5;
        out[(b * PP + h) * NN + n] = val + offL[h];
    }
}

extern "C" void kernel_launch(void* const* d_in, const int* in_sizes, int n_in,
                              void* d_out, int out_size, void* d_ws, size_t ws_size,
                              hipStream_t stream) {
    const float* q  = (const float*)d_in[0];
    const float* k  = (const float*)d_in[1];
    const float* v  = (const float*)d_in[2];
    const int* mask = (const int*)d_in[3];
    const float* Wq = (const float*)d_in[4];
    const float* bq = (const float*)d_in[5];
    const float* Wk = (const float*)d_in[6];
    const float* bk = (const float*)d_in[7];
    const float* Wv = (const float*)d_in[8];
    const float* bv = (const float*)d_in[9];
    const float* Wc = (const float*)d_in[10];
    const float* bc = (const float*)d_in[11];
    const float* Wf = (const float*)d_in[12];
    const float* bf = (const float*)d_in[13];
    float* out = (float*)d_out;
    (void)bk;  // bk only fed the g2 column, which cancels in softmax

    dim3 grid(BB * NN / 32), block(256);
    hipLaunchKernelGGL(mha_kernel, grid, block, 0, stream,
                       q, k, v, mask, Wq, bq, Wk, bk, Wv, bv, Wc, bc, Wf, bf, out);
}